// Round 14
// baseline (182.529 us; speedup 1.0000x reference)
//
#include <hip/hip_runtime.h>

typedef unsigned short ushort_t;
typedef __bf16 bf16x8 __attribute__((ext_vector_type(8)));
typedef float f32x4 __attribute__((ext_vector_type(4)));

#define BB 4
#define TT 2048
#define DIMD 1024
#define NH 16
#define DK 64
#define MROWS (BB * TT)   /* 8192 */
#define NQKV (3 * DIMD)   /* 3072 */

__device__ __forceinline__ ushort_t f2b(float f) {
  __bf16 h = (__bf16)f;
  union { __bf16 h; ushort_t u; } c; c.h = h; return c.u;
}
__device__ __forceinline__ float fexp2(float x) {   // v_exp_f32: 2^x
  float r;
  asm("v_exp_f32 %0, %1" : "=v"(r) : "v"(x));
  return r;
}

// async global->LDS, 16B per lane; LDS dest is wave-uniform base + lane*16
__device__ __forceinline__ void gload_lds16(const void* g, void* l) {
  __builtin_amdgcn_global_load_lds(
      (const __attribute__((address_space(1))) void*)g,
      (__attribute__((address_space(3))) void*)l,
      16, 0, 0);
}

// f32 -> bf16 downcast, 8 elems/thread (n % 2048 == 0)
__global__ __launch_bounds__(256) void cast_f32_bf16(
    const float* __restrict__ in, ushort_t* __restrict__ out, int n)
{
  const int i = (blockIdx.x * 256 + threadIdx.x) * 8;
  if (i >= n) return;
  float4 a = *(const float4*)(in + i);
  float4 b = *(const float4*)(in + i + 4);
  ushort_t o[8];
  o[0] = f2b(a.x); o[1] = f2b(a.y); o[2] = f2b(a.z); o[3] = f2b(a.w);
  o[4] = f2b(b.x); o[5] = f2b(b.y); o[6] = f2b(b.z); o[7] = f2b(b.w);
  *(uint4*)(out + i) = *(const uint4*)o;
}

// ---------------- GEMM 128x256: triple-buffer, 1 barrier/K-tile -------------
// L2-friendly mapping: XCD x owns bm in [x*8, x*8+8) forever (A-band 2MB hot);
// bn advances every 8 blocks (W-panel hot for its 8 consecutive users).
// Requires M/128 == 64 and grid % 8 == 0.
template <bool OUT_F32>
__global__ __launch_bounds__(512, 4) void gemm_bt_pipe(
    const ushort_t* __restrict__ A, const ushort_t* __restrict__ W,
    const float* __restrict__ bias, void* __restrict__ Cp,
    int M, int N, int K)
{
  __shared__ __align__(16) ushort_t As[3][128 * 32];
  __shared__ __align__(16) ushort_t Bs[3][256 * 32];

  const int tid = threadIdx.x;
  const int wave = tid >> 6, lane = tid & 63;
  const int x = blockIdx.x & 7, j = blockIdx.x >> 3;   // XCD id, local index
  const int bm = (x << 3) | (j & 7);
  const int bn = j >> 3;
  const int row0 = bm << 7, col0 = bn << 8;
  const int wm = (wave >> 2) << 6;   // 0 / 64
  const int wn = (wave & 3) << 6;    // 0,64,128,192
  const int fr = lane & 15;
  const int g  = lane >> 4;
  const int g4 = g << 2;
  const int csw = (g ^ (fr >> 2)) << 3;   // fragment-read chunk swizzle (elems)

  const int srow = lane >> 2;
  const int scol = ((lane & 3) ^ ((lane >> 4) & 3)) << 3;
  const int lbase = wave << 9;            // wave-uniform LDS elem base

  const ushort_t* Ag  = A + (size_t)(row0 + (wave << 4) + srow) * K + scol;
  const ushort_t* Wg0 = W + (size_t)(col0 + (wave << 4) + srow) * K + scol;
  const ushort_t* Wg1 = Wg0 + (size_t)128 * K;

#define STAGE_P(kt, buf)                                                      \
  {                                                                           \
    const size_t _k = (size_t)(kt) << 5;                                      \
    gload_lds16(Ag + _k,  &As[buf][lbase]);                                   \
    gload_lds16(Wg0 + _k, &Bs[buf][lbase]);                                   \
    gload_lds16(Wg1 + _k, &Bs[buf][4096 + lbase]);                            \
  }

  const int NT = K >> 5;
  STAGE_P(0, 0);
  STAGE_P(1, 1);

  f32x4 acc[4][4] = {};
  int cr = 0, st = 2;

  for (int t = 0; t < NT; ++t) {
    if (t + 1 < NT) asm volatile("s_waitcnt vmcnt(3)" ::: "memory");
    else            asm volatile("s_waitcnt vmcnt(0)" ::: "memory");
    __builtin_amdgcn_s_barrier();

    const ushort_t* as_ = As[cr];
    const ushort_t* bs_ = Bs[cr];
    bf16x8 af0 = *(const bf16x8*)&as_[(wm +      fr) * 32 + csw];
    bf16x8 af1 = *(const bf16x8*)&as_[(wm + 16 + fr) * 32 + csw];
    bf16x8 bw0 = *(const bf16x8*)&bs_[(wn +      fr) * 32 + csw];
    bf16x8 bw1 = *(const bf16x8*)&bs_[(wn + 16 + fr) * 32 + csw];
    bf16x8 bw2 = *(const bf16x8*)&bs_[(wn + 32 + fr) * 32 + csw];
    bf16x8 bw3 = *(const bf16x8*)&bs_[(wn + 48 + fr) * 32 + csw];
    if (t + 2 < NT) STAGE_P(t + 2, st);
    asm volatile("s_waitcnt lgkmcnt(0)" ::: "memory");
    __builtin_amdgcn_sched_barrier(0);
    __builtin_amdgcn_s_setprio(1);
    acc[0][0] = __builtin_amdgcn_mfma_f32_16x16x32_bf16(af0, bw0, acc[0][0], 0, 0, 0);
    acc[0][1] = __builtin_amdgcn_mfma_f32_16x16x32_bf16(af0, bw1, acc[0][1], 0, 0, 0);
    acc[0][2] = __builtin_amdgcn_mfma_f32_16x16x32_bf16(af0, bw2, acc[0][2], 0, 0, 0);
    acc[0][3] = __builtin_amdgcn_mfma_f32_16x16x32_bf16(af0, bw3, acc[0][3], 0, 0, 0);
    acc[1][0] = __builtin_amdgcn_mfma_f32_16x16x32_bf16(af1, bw0, acc[1][0], 0, 0, 0);
    acc[1][1] = __builtin_amdgcn_mfma_f32_16x16x32_bf16(af1, bw1, acc[1][1], 0, 0, 0);
    acc[1][2] = __builtin_amdgcn_mfma_f32_16x16x32_bf16(af1, bw2, acc[1][2], 0, 0, 0);
    acc[1][3] = __builtin_amdgcn_mfma_f32_16x16x32_bf16(af1, bw3, acc[1][3], 0, 0, 0);
    __builtin_amdgcn_s_setprio(0);

    bf16x8 af2 = *(const bf16x8*)&as_[(wm + 32 + fr) * 32 + csw];
    bf16x8 af3 = *(const bf16x8*)&as_[(wm + 48 + fr) * 32 + csw];
    asm volatile("s_waitcnt lgkmcnt(0)" ::: "memory");
    __builtin_amdgcn_sched_barrier(0);
    __builtin_amdgcn_s_setprio(1);
    acc[2][0] = __builtin_amdgcn_mfma_f32_16x16x32_bf16(af2, bw0, acc[2][0], 0, 0, 0);
    acc[2][1] = __builtin_amdgcn_mfma_f32_16x16x32_bf16(af2, bw1, acc[2][1], 0, 0, 0);
    acc[2][2] = __builtin_amdgcn_mfma_f32_16x16x32_bf16(af2, bw2, acc[2][2], 0, 0, 0);
    acc[2][3] = __builtin_amdgcn_mfma_f32_16x16x32_bf16(af2, bw3, acc[2][3], 0, 0, 0);
    acc[3][0] = __builtin_amdgcn_mfma_f32_16x16x32_bf16(af3, bw0, acc[3][0], 0, 0, 0);
    acc[3][1] = __builtin_amdgcn_mfma_f32_16x16x32_bf16(af3, bw1, acc[3][1], 0, 0, 0);
    acc[3][2] = __builtin_amdgcn_mfma_f32_16x16x32_bf16(af3, bw2, acc[3][2], 0, 0, 0);
    acc[3][3] = __builtin_amdgcn_mfma_f32_16x16x32_bf16(af3, bw3, acc[3][3], 0, 0, 0);
    __builtin_amdgcn_s_setprio(0);

    ++cr; if (cr == 3) cr = 0;
    ++st; if (st == 3) st = 0;
  }
#undef STAGE_P

#pragma unroll
  for (int jj = 0; jj < 4; ++jj) {
    const int col = col0 + wn + (jj << 4) + fr;
    const float bv = bias[col];
#pragma unroll
    for (int i = 0; i < 4; ++i)
#pragma unroll
      for (int r = 0; r < 4; ++r) {
        const size_t row = (size_t)(row0 + wm + (i << 4) + g4 + r);
        if constexpr (OUT_F32)
          ((float*)Cp)[row * (size_t)N + col] = acc[i][jj][r] + bv;
        else
          ((ushort_t*)Cp)[row * (size_t)N + col] = f2b(acc[i][jj][r] + bv);
      }
  }
}

// ---------------- Flash attention: single barrier per kt (dbuf Ks AND Vt) ---
// Race ledger: all waves sit between barrier(kt) and barrier(kt+1) together.
//  - QK reads Ks[kt&1];   K-DMA(kt+1) writes Ks[(kt+1)&1]  -> disjoint.
//  - PV reads Vt[kt&1];   scatter V(kt+1) writes Vt[(kt+1)&1] -> disjoint.
//  - trailing lgkmcnt(0) (unconditional, incl. skip-waves) drains scatters
//    before the next barrier; vmcnt(0) at top drains K-DMA(kt)+va(kt+1),
//    both issued a full softmax+PV phase earlier (latency covered).
#define C1 0.18033688011112042f   /* 0.125 * log2(e) */
__global__ __launch_bounds__(512, 4) void attn_fused(
    const ushort_t* __restrict__ qkv, ushort_t* __restrict__ ctx)
{
  __shared__ __align__(16) ushort_t Qs[128 * 64];
  __shared__ __align__(16) ushort_t Ks[2][64 * 64];
  __shared__ __align__(16) ushort_t Vt[2][64 * 64];    // Vt[buf][d][kv], hh-swizzled
  __shared__ __align__(16) ushort_t Ps[8][16 * 64];    // per-wave private

  const int tid = threadIdx.x, wave = tid >> 6, lane = tid & 63;
  const int fr = lane & 15;
  const int g  = lane >> 4;
  const int fk = g << 3;
  const int g4 = g << 2;

  const int bid = blockIdx.x;
  const int bq  = (bid >> 3) & 7;
  const int G   = (bid & 7) | ((bid >> 6) << 3);
  const int h   = G & 15;
  const int b   = G >> 4;

  const int srl = lane >> 3;
  const int scc = ((lane & 7) ^ srl) << 3;
  const int vr  = tid >> 3;
  const int vc  = (tid & 7) << 3;
  const int rsw = (fr & 7) << 3;

  const ushort_t* Kg = qkv + (size_t)b * TT * NQKV + DIMD + h * DK;
  const ushort_t* Vg = qkv + (size_t)b * TT * NQKV + 2 * DIMD + h * DK;

#pragma unroll 1
  for (int t = 0; t < 2; ++t) {
    const int qt = t ? (15 - bq) : bq;
    const int ktmax = 2 * qt + 1;
    const int diag  = 2 * qt + (wave >> 2);
    const size_t qrow0 = (size_t)b * TT + (size_t)qt * 128;

    __syncthreads();   // prior q-tile's LDS fully consumed

    // prologue: V(0) regs + Q,K(0) DMA
    const ushort_t* Qg = qkv + qrow0 * NQKV + h * DK;
    uint4 va = *(const uint4*)(Vg + (size_t)vr * NQKV + vc);     // V(0)
#pragma unroll
    for (int pp = 0; pp < 2; ++pp) {
      const int e  = (wave << 9) + (pp << 12);
      const int rr = (e >> 6) + srl;
      gload_lds16(Qg + (size_t)rr * NQKV + scc, Qs + e);
    }
    {
      const int e  = wave << 9;
      const int rr = (wave << 3) + srl;
      gload_lds16(Kg + (size_t)rr * NQKV + scc, Ks[0] + e);
    }
    asm volatile("s_waitcnt vmcnt(0)" ::: "memory");
    __syncthreads();   // Q, K(0) staged

    bf16x8 aqr[2];
#pragma unroll
    for (int ks = 0; ks < 2; ++ks)
      aqr[ks] = *(const bf16x8*)&Qs[((wave << 4) + fr) * 64 + (((ks << 5) + fk) ^ rsw)];

    // scatter V(0) -> Vt[0]; prefetch V(1)
    {
      __align__(16) ushort_t tmp[8];
      *(uint4*)tmp = va;
#pragma unroll
      for (int jj = 0; jj < 8; ++jj) {
        const int d  = vc + jj;
        const int hh = (d & 7) ^ ((d >> 3) & 7);
        Vt[0][d * 64 + (vr ^ (hh << 3))] = tmp[jj];
      }
    }
    va = *(const uint4*)(Vg + (size_t)(64 + vr) * NQKV + vc);    // V(1) (ktmax>=1 always)
    asm volatile("s_waitcnt lgkmcnt(0)" ::: "memory");           // scatter landed

    const int qrow = (qt << 7) + (wave << 4) + fr;
    float mrow = -1e30f, lrow = 0.f;
    f32x4 oacc[4] = {};

    for (int kt = 0; kt <= ktmax; ++kt) {
      asm volatile("s_waitcnt vmcnt(0)" ::: "memory");   // K-DMA(kt), va ready (covered)
      __builtin_amdgcn_s_barrier();                      // scatter(kt)/DMA(kt) visible

      const int cur = kt & 1, nxt = cur ^ 1;
      f32x4 s[4];

      if (kt <= diag) {   // S^T = mfma(K, Q)
#pragma unroll
        for (int ni = 0; ni < 4; ++ni) s[ni] = f32x4{0.f, 0.f, 0.f, 0.f};
        __builtin_amdgcn_s_setprio(1);
#pragma unroll
        for (int ks = 0; ks < 2; ++ks)
#pragma unroll
          for (int ni = 0; ni < 4; ++ni) {
            const bf16x8 bk = *(const bf16x8*)&Ks[cur][((ni << 4) + fr) * 64 + (((ks << 5) + fk) ^ rsw)];
            s[ni] = __builtin_amdgcn_mfma_f32_16x16x32_bf16(bk, aqr[ks], s[ni], 0, 0, 0);
          }
        __builtin_amdgcn_s_setprio(0);
      }

      // issue K-DMA(kt+1) + scatter V(kt+1) + prefetch V(kt+2)
      if (kt < ktmax) {
        const size_t krow = (size_t)(kt + 1) << 6;
        const int e  = wave << 9;
        const int rr = (wave << 3) + srl;
        gload_lds16(Kg + (krow + rr) * NQKV + scc, Ks[nxt] + e);
        {
          __align__(16) ushort_t tmp[8];
          *(uint4*)tmp = va;
#pragma unroll
          for (int jj = 0; jj < 8; ++jj) {
            const int d  = vc + jj;
            const int hh = (d & 7) ^ ((d >> 3) & 7);
            Vt[nxt][d * 64 + (vr ^ (hh << 3))] = tmp[jj];
          }
        }
        if (kt + 1 < ktmax)
          va = *(const uint4*)(Vg + ((size_t)(kt + 2) * 64 + vr) * NQKV + vc);
      }

      if (kt <= diag) {
        if (kt == diag) {   // mask only the diagonal tile
          const int kb = kt << 6;
#pragma unroll
          for (int ni = 0; ni < 4; ++ni)
#pragma unroll
            for (int r = 0; r < 4; ++r) {
              const int kc = kb + (ni << 4) + g4 + r;
              if (kc > qrow) s[ni][r] = -1e30f;
            }
        }

        float rm = -1e30f;
#pragma unroll
        for (int ni = 0; ni < 4; ++ni) {
          const float m01 = fmaxf(s[ni][0], s[ni][1]);
          const float m23 = fmaxf(s[ni][2], s[ni][3]);
          rm = fmaxf(rm, fmaxf(m01, m23));
        }
        rm = fmaxf(rm, __shfl_xor(rm, 16, 64));
        rm = fmaxf(rm, __shfl_xor(rm, 32, 64));

        if (__any(rm > mrow + 64.f)) {   // defer-max (THR = 8 scaled = 64 raw)
          const float mn = fmaxf(mrow, rm);
          const float corr = fexp2((mrow - mn) * C1);
          mrow = mn;
          lrow *= corr;
#pragma unroll
          for (int ni = 0; ni < 4; ++ni) oacc[ni] *= corr;
        }
        const float nm2 = -mrow * C1;
        float rs = 0.f;
#pragma unroll
        for (int ni = 0; ni < 4; ++ni)
#pragma unroll
          for (int r = 0; r < 4; ++r) {
            const float pe = fexp2(fmaf(s[ni][r], C1, nm2));
            s[ni][r] = pe;
            rs += pe;
          }
        rs += __shfl_xor(rs, 16, 64);
        rs += __shfl_xor(rs, 32, 64);
        lrow += rs;

#pragma unroll
        for (int ni = 0; ni < 4; ++ni) {
          ushort_t o4[4];
#pragma unroll
          for (int r = 0; r < 4; ++r) o4[r] = f2b(s[ni][r]);
          *(uint2*)&Ps[wave][fr * 64 + (((ni << 4) + g4) ^ rsw)] = *(const uint2*)o4;
        }
        asm volatile("s_waitcnt lgkmcnt(0)" ::: "memory");
        __builtin_amdgcn_sched_barrier(0);

        __builtin_amdgcn_s_setprio(1);
#pragma unroll
        for (int ks = 0; ks < 2; ++ks) {
          const bf16x8 ap = *(const bf16x8*)&Ps[wave][fr * 64 + (((ks << 5) + fk) ^ rsw)];
#pragma unroll
          for (int ni = 0; ni < 4; ++ni) {
            const int hh = (fr & 7) ^ ((2 * ni + (fr >> 3)) & 7);
            const bf16x8 bv = *(const bf16x8*)&Vt[cur][((ni << 4) + fr) * 64 + (((ks << 5) + fk) ^ (hh << 3))];
            oacc[ni] = __builtin_amdgcn_mfma_f32_16x16x32_bf16(bv, ap, oacc[ni], 0, 0, 0);
          }
        }
        __builtin_amdgcn_s_setprio(0);
      }

      // unconditional: ALL waves' LDS writes (scatter) drained before next barrier
      asm volatile("s_waitcnt lgkmcnt(0)" ::: "memory");
    }

    const float inv = 1.f / lrow;
    ushort_t* crow = ctx + (qrow0 + (wave << 4) + fr) * DIMD + h * DK;
#pragma unroll
    for (int ni = 0; ni < 4; ++ni) {
      ushort_t o4[4];
#pragma unroll
      for (int r = 0; r < 4; ++r) o4[r] = f2b(oacc[ni][r] * inv);
      *(uint2*)&crow[(ni << 4) + g4] = *(const uint2*)o4;
    }
  }
}

extern "C" void kernel_launch(void* const* d_in, const int* in_sizes, int n_in,
                              void* d_out, int out_size, void* d_ws, size_t ws_size,
                              hipStream_t stream) {
  const float* x     = (const float*)d_in[0];
  const float* w_qkv = (const float*)d_in[1];
  const float* b_qkv = (const float*)d_in[2];
  const float* w_out = (const float*)d_in[3];
  const float* b_out = (const float*)d_in[4];

  const size_t need = 36u * 1024 * 1024 * sizeof(ushort_t);   // 72 MiB
  if (ws_size < need) return;

  ushort_t* qkv = (ushort_t*)d_ws;
  ushort_t* xb  = qkv + (size_t)MROWS * NQKV;
  ushort_t* wqb = xb  + (size_t)MROWS * DIMD;
  ushort_t* wob = wqb + (size_t)NQKV * DIMD;
  ushort_t* ctx = xb;
  float*    out = (float*)d_out;

  cast_f32_bf16<<<dim3(MROWS * DIMD / 2048), dim3(256), 0, stream>>>(x, xb, MROWS * DIMD);
  cast_f32_bf16<<<dim3(NQKV * DIMD / 2048), dim3(256), 0, stream>>>(w_qkv, wqb, NQKV * DIMD);
  cast_f32_bf16<<<dim3(DIMD * DIMD / 2048), dim3(256), 0, stream>>>(w_out, wob, DIMD * DIMD);
  // 1) QKV projection — 128x256 triple-buffer pipeline (grid 768)
  gemm_bt_pipe<false><<<dim3((MROWS / 128) * (NQKV / 256)), dim3(512), 0, stream>>>(
      xb, wqb, b_qkv, (void*)qkv, MROWS, NQKV, DIMD);
  // 2) causal flash attention
  attn_fused<<<dim3(BB * NH * 8), dim3(512), 0, stream>>>(qkv, ctx);
  // 3) output projection — same pipeline (grid 256)
  gemm_bt_pipe<true><<<dim3((MROWS / 128) * (DIMD / 256)), dim3(512), 0, stream>>>(
      ctx, wob, b_out, (void*)out, MROWS, DIMD, DIMD);
}